// Round 1
// baseline (402.210 us; speedup 1.0000x reference)
//
#include <hip/hip_runtime.h>

// Problem constants (fixed by reference setup_inputs)
#define BN 32768      // batch
#define DN 1024       // feature dim
#define CN 256        // num classes
#define RCAP 1024     // max class size we track (mean 128, std ~11; >1024 impossible)

__device__ __forceinline__ float dot4(float4 a, float4 b) {
    return a.x*b.x + a.y*b.y + a.z*b.z + a.w*b.w;
}

// ---------------------------------------------------------------------------
// KC: per-class ordered compaction (one wave per class) + counts + zero acc
// idx[c*RCAP + r] = global index of r-th member of class c (order of appearance)
// ---------------------------------------------------------------------------
__global__ void __launch_bounds__(64) kc_compact(const int* __restrict__ labels,
                                                 int* __restrict__ idx,
                                                 int* __restrict__ counts,
                                                 float* __restrict__ acc) {
    const int c = blockIdx.x;
    const int lane = threadIdx.x;
    const unsigned long long lt = (lane == 0) ? 0ull : (~0ull >> (64 - lane));
    int base = 0;
    for (int ch = 0; ch < BN; ch += 64) {
        const int i = ch + lane;
        const bool pred = (labels[i] == c);
        const unsigned long long mask = __ballot(pred);
        if (pred) {
            const int pos = base + __popcll(mask & lt);
            if (pos < RCAP) idx[c * RCAP + pos] = i;
        }
        base += __popcll(mask);
    }
    if (lane == 0) {
        counts[c] = base;
        if (c == 0) *acc = 0.0f;
    }
}

// ---------------------------------------------------------------------------
// K1: per-row inverse norm. One wave per row, 4 rows per 256-thread block.
// ---------------------------------------------------------------------------
__global__ void __launch_bounds__(256) k_rnorm(const float4* __restrict__ x4,
                                               float* __restrict__ rnorm) {
    const int wave = threadIdx.x >> 6;
    const int lane = threadIdx.x & 63;
    const int row = blockIdx.x * 4 + wave;
    const float4* base = x4 + (size_t)row * (DN / 4);
    float ss = 0.0f;
#pragma unroll
    for (int j = 0; j < 4; ++j) {
        float4 v = base[lane + j * 64];
        ss += dot4(v, v);
    }
#pragma unroll
    for (int off = 32; off; off >>= 1) ss += __shfl_xor(ss, off, 64);
    if (lane == 0) rnorm[row] = 1.0f / fmaxf(sqrtf(ss), 1e-12f);
}

// ---------------------------------------------------------------------------
// KS: per-class sums S_c (register accumulation, gather via idx), ||S_c||^2,
// and closed-form class contribution (n - ||S||^2/n)/D added to acc.
// One block of 1024 threads per class; thread owns a col-quad; 4 row-groups.
// ---------------------------------------------------------------------------
__global__ void __launch_bounds__(1024) k_sums(const float4* __restrict__ x4,
                                               const float* __restrict__ rnorm,
                                               const int* __restrict__ idx,
                                               const int* __restrict__ counts,
                                               float* __restrict__ sums,
                                               float* __restrict__ snorm2,
                                               float* __restrict__ acc) {
    const int c = blockIdx.x;
    const int n = counts[c];
    const int nn = min(n, RCAP);
    const int tq = threadIdx.x & 255;   // col-quad 0..255 (4 floats each)
    const int grp = threadIdx.x >> 8;   // 0..3 row groups
    const int* ic = idx + c * RCAP;

    float4 a = make_float4(0.f, 0.f, 0.f, 0.f);
    for (int r = grp; r < nn; r += 4) {
        const int row = ic[r];
        const float rn = rnorm[row];
        const float4 v = x4[(size_t)row * 256 + tq];
        a.x += v.x * rn; a.y += v.y * rn; a.z += v.z * rn; a.w += v.w * rn;
    }

    __shared__ float4 red[4][256];
    red[grp][tq] = a;
    __syncthreads();

    float d = 0.0f;
    if (grp == 0) {
        float4 t0 = red[0][tq], t1 = red[1][tq], t2 = red[2][tq], t3 = red[3][tq];
        float4 tot;
        tot.x = t0.x + t1.x + t2.x + t3.x;
        tot.y = t0.y + t1.y + t2.y + t3.y;
        tot.z = t0.z + t1.z + t2.z + t3.z;
        tot.w = t0.w + t1.w + t2.w + t3.w;
        ((float4*)sums)[(size_t)c * 256 + tq] = tot;
        d = dot4(tot, tot);
    }
    // wave-level reduce (grp!=0 contributes zeros within its own waves)
#pragma unroll
    for (int off = 32; off; off >>= 1) d += __shfl_xor(d, off, 64);
    __shared__ float wsum[4];
    if (grp == 0 && (tq & 63) == 0) wsum[tq >> 6] = d;
    __syncthreads();
    if (threadIdx.x == 0) {
        const float s2 = wsum[0] + wsum[1] + wsum[2] + wsum[3];
        snorm2[c] = s2;
        if (n > 1) {
            const float nf = (float)n;
            atomicAdd(acc, (nf - s2 / nf) * (1.0f / DN));
        }
    }
}

// ---------------------------------------------------------------------------
// K5: exclusion corrections. Row i has exclusion iff i < counts[labels[i]]
// (~128 rows). delta = dist_corrected - dist_naive; ||f_i||^2 cancels.
// One 256-thread block per candidate row i in [0, 2048).
// ---------------------------------------------------------------------------
__global__ void __launch_bounds__(256) k_corr(const float4* __restrict__ x4,
                                              const int* __restrict__ labels,
                                              const int* __restrict__ counts,
                                              const int* __restrict__ idx,
                                              const float* __restrict__ rnorm,
                                              const float* __restrict__ sums,
                                              const float* __restrict__ snorm2,
                                              float* __restrict__ acc) {
    const int i = blockIdx.x;
    const int c = labels[i];
    const int n = counts[c];
    if (i >= n || n < 2 || i >= RCAP) return;  // no exclusion or contrib==0
    const int k = idx[c * RCAP + i];
    const int t = threadIdx.x;

    const float4 xi = x4[(size_t)i * 256 + t];
    const float4 xk = x4[(size_t)k * 256 + t];
    const float4 s  = ((const float4*)sums)[(size_t)c * 256 + t];

    float d0 = dot4(xi, s);
    float d1 = dot4(xi, xk);
    float d2 = dot4(xk, s);
    float d3 = dot4(xk, xk);
#pragma unroll
    for (int off = 32; off; off >>= 1) {
        d0 += __shfl_xor(d0, off, 64);
        d1 += __shfl_xor(d1, off, 64);
        d2 += __shfl_xor(d2, off, 64);
        d3 += __shfl_xor(d3, off, 64);
    }
    __shared__ float4 wred[4];
    if ((t & 63) == 0) wred[t >> 6] = make_float4(d0, d1, d2, d3);
    __syncthreads();
    if (t == 0) {
        const float xiS  = wred[0].x + wred[1].x + wred[2].x + wred[3].x;
        const float xixk = wred[0].y + wred[1].y + wred[2].y + wred[3].y;
        const float xkS  = wred[0].z + wred[1].z + wred[2].z + wred[3].z;
        const float xkxk = wred[0].w + wred[1].w + wred[2].w + wred[3].w;
        const float rni = rnorm[i], rnk = rnorm[k], s2 = snorm2[c];
        const float fiS  = rni * xiS;
        const float fifk = rni * rnk * xixk;
        const float Sfk  = rnk * xkS;
        const float fk2  = rnk * rnk * xkxk;
        const float nf = (float)n;
        const float dd = nf - 1.0f;
        const float naive = -2.0f * fiS / nf + s2 / (nf * nf);
        const float corr  = -2.0f * (fiS - fifk) / dd + (s2 - 2.0f * Sfk + fk2) / (dd * dd);
        atomicAdd(acc, (corr - naive) * (1.0f / DN));
    }
}

// ---------------------------------------------------------------------------
// K6: finalize scalar output
// ---------------------------------------------------------------------------
__global__ void k_fin(const float* __restrict__ acc, float* __restrict__ out) {
    out[0] = (0.0005f / (float)BN) * acc[0];
}

extern "C" void kernel_launch(void* const* d_in, const int* in_sizes, int n_in,
                              void* d_out, int out_size, void* d_ws, size_t ws_size,
                              hipStream_t stream) {
    const float* features = (const float*)d_in[0];
    const int* labels = (const int*)d_in[1];
    float* out = (float*)d_out;

    // ws layout (bytes):
    char* ws = (char*)d_ws;
    float* rnorm  = (float*)(ws + 0);                 // 32768 f  -> 131072
    float* sums   = (float*)(ws + 131072);            // 262144 f -> +1 MiB = 1179648
    int*   idx    = (int*)  (ws + 1179648);           // 256*1024 i -> +1 MiB = 2228224
    int*   counts = (int*)  (ws + 2228224);           // 256 i -> 2229248
    float* snorm2 = (float*)(ws + 2229248);           // 256 f -> 2230272
    float* acc    = (float*)(ws + 2230272);           // 1 f

    const float4* x4 = (const float4*)features;

    kc_compact<<<CN, 64, 0, stream>>>(labels, idx, counts, acc);
    k_rnorm<<<BN / 4, 256, 0, stream>>>(x4, rnorm);
    k_sums<<<CN, 1024, 0, stream>>>(x4, rnorm, idx, counts, sums, snorm2, acc);
    k_corr<<<2048, 256, 0, stream>>>(x4, labels, counts, idx, rnorm, sums, snorm2, acc);
    k_fin<<<1, 1, 0, stream>>>(acc, out);
}

// Round 2
// 231.014 us; speedup vs baseline: 1.7411x; 1.7411x over previous
//
#include <hip/hip_runtime.h>

// Problem constants (fixed by reference setup_inputs)
#define BN 32768      // batch
#define DN 1024       // feature dim
#define CN 256        // num classes
#define RCAP 1024     // max class size we track (mean 128, std ~11; >1024 impossible)

__device__ __forceinline__ float dot4(float4 a, float4 b) {
    return a.x*b.x + a.y*b.y + a.z*b.z + a.w*b.w;
}

// ---------------------------------------------------------------------------
// KC: per-class ordered compaction + counts + zero acc.
// One block (256 thr / 4 waves) per class. Labels staged into LDS packed as
// bytes (32 KB); each wave scans 1/4 of the batch: count pass -> wave prefix
// -> write pass. All ballot work runs at LDS latency, staging is one
// coalesced 128 KB read (L2-resident after first block touches it).
// ---------------------------------------------------------------------------
__global__ void __launch_bounds__(256) kc_compact(const int* __restrict__ labels,
                                                  int* __restrict__ idx,
                                                  int* __restrict__ counts,
                                                  float* __restrict__ acc) {
    __shared__ unsigned int packed[BN / 4];   // 32 KB: 4 labels per word
    __shared__ int wcnt[4];
    const int c = blockIdx.x;
    const int t = threadIdx.x;

    // stage: 8192 words / 256 threads = 32 int4 loads per thread
    for (int w = t; w < BN / 4; w += 256) {
        const int4 v = ((const int4*)labels)[w];
        packed[w] = (unsigned int)(v.x & 255)
                  | ((unsigned int)(v.y & 255) << 8)
                  | ((unsigned int)(v.z & 255) << 16)
                  | ((unsigned int)(v.w & 255) << 24);
    }
    __syncthreads();

    const int wave = t >> 6, lane = t & 63;
    const unsigned long long lt = (lane == 0) ? 0ull : (~0ull >> (64 - lane));
    const int ch0 = wave * 128, ch1 = ch0 + 128;   // 128 chunks of 64 per wave

    // pass 1: count
    int cnt = 0;
    for (int ch = ch0; ch < ch1; ++ch) {
        const int gi = ch * 64 + lane;
        const int lab = (packed[gi >> 2] >> ((gi & 3) * 8)) & 255;
        cnt += __popcll(__ballot(lab == c));
    }
    if (lane == 0) wcnt[wave] = cnt;
    __syncthreads();

    int base = 0;
    for (int w2 = 0; w2 < wave; ++w2) base += wcnt[w2];

    // pass 2: write ordered member list
    for (int ch = ch0; ch < ch1; ++ch) {
        const int gi = ch * 64 + lane;
        const int lab = (packed[gi >> 2] >> ((gi & 3) * 8)) & 255;
        const bool pred = (lab == c);
        const unsigned long long mask = __ballot(pred);
        if (pred) {
            const int pos = base + __popcll(mask & lt);
            if (pos < RCAP) idx[c * RCAP + pos] = gi;
        }
        base += __popcll(mask);
    }

    if (t == 0) {
        counts[c] = wcnt[0] + wcnt[1] + wcnt[2] + wcnt[3];
        if (c == 0) *acc = 0.0f;
    }
}

// ---------------------------------------------------------------------------
// K1: per-row inverse norm. One wave per row, 4 rows per 256-thread block.
// ---------------------------------------------------------------------------
__global__ void __launch_bounds__(256) k_rnorm(const float4* __restrict__ x4,
                                               float* __restrict__ rnorm) {
    const int wave = threadIdx.x >> 6;
    const int lane = threadIdx.x & 63;
    const int row = blockIdx.x * 4 + wave;
    const float4* base = x4 + (size_t)row * (DN / 4);
    float ss = 0.0f;
#pragma unroll
    for (int j = 0; j < 4; ++j) {
        float4 v = base[lane + j * 64];
        ss += dot4(v, v);
    }
#pragma unroll
    for (int off = 32; off; off >>= 1) ss += __shfl_xor(ss, off, 64);
    if (lane == 0) rnorm[row] = 1.0f / fmaxf(sqrtf(ss), 1e-12f);
}

// ---------------------------------------------------------------------------
// KS: per-class sums S_c (register accumulation, gather via idx), ||S_c||^2,
// and closed-form class contribution (n - ||S||^2/n)/D added to acc.
// One block of 1024 threads per class; thread owns a col-quad; 4 row-groups.
// Index list + rnorms staged to LDS first so gather addresses are
// loop-independent (lets the compiler keep many dwordx4 loads in flight).
// ---------------------------------------------------------------------------
__global__ void __launch_bounds__(1024) k_sums(const float4* __restrict__ x4,
                                               const float* __restrict__ rnorm,
                                               const int* __restrict__ idx,
                                               const int* __restrict__ counts,
                                               float* __restrict__ sums,
                                               float* __restrict__ snorm2,
                                               float* __restrict__ acc) {
    __shared__ int sic[RCAP];
    __shared__ float srn[RCAP];
    const int c = blockIdx.x;
    const int n = counts[c];
    const int nn = min(n, RCAP);
    const int tq = threadIdx.x & 255;   // col-quad 0..255 (4 floats each)
    const int grp = threadIdx.x >> 8;   // 0..3 row groups

    if ((int)threadIdx.x < nn) {
        const int row = idx[c * RCAP + threadIdx.x];
        sic[threadIdx.x] = row;
        srn[threadIdx.x] = rnorm[row];
    }
    __syncthreads();

    float4 a = make_float4(0.f, 0.f, 0.f, 0.f);
    for (int r = grp; r < nn; r += 4) {
        const int row = sic[r];
        const float rn = srn[r];
        const float4 v = x4[(size_t)row * 256 + tq];
        a.x += v.x * rn; a.y += v.y * rn; a.z += v.z * rn; a.w += v.w * rn;
    }

    __shared__ float4 red[4][256];
    red[grp][tq] = a;
    __syncthreads();

    float d = 0.0f;
    if (grp == 0) {
        float4 t0 = red[0][tq], t1 = red[1][tq], t2 = red[2][tq], t3 = red[3][tq];
        float4 tot;
        tot.x = t0.x + t1.x + t2.x + t3.x;
        tot.y = t0.y + t1.y + t2.y + t3.y;
        tot.z = t0.z + t1.z + t2.z + t3.z;
        tot.w = t0.w + t1.w + t2.w + t3.w;
        ((float4*)sums)[(size_t)c * 256 + tq] = tot;
        d = dot4(tot, tot);
    }
#pragma unroll
    for (int off = 32; off; off >>= 1) d += __shfl_xor(d, off, 64);
    __shared__ float wsum[4];
    if (grp == 0 && (tq & 63) == 0) wsum[tq >> 6] = d;
    __syncthreads();
    if (threadIdx.x == 0) {
        const float s2 = wsum[0] + wsum[1] + wsum[2] + wsum[3];
        snorm2[c] = s2;
        if (n > 1) {
            const float nf = (float)n;
            atomicAdd(acc, (nf - s2 / nf) * (1.0f / DN));
        }
    }
}

// ---------------------------------------------------------------------------
// K5: exclusion corrections. Row i has exclusion iff i < counts[labels[i]]
// (~128 rows). delta = dist_corrected - dist_naive; ||f_i||^2 cancels.
// One 256-thread block per candidate row i in [0, 2048).
// ---------------------------------------------------------------------------
__global__ void __launch_bounds__(256) k_corr(const float4* __restrict__ x4,
                                              const int* __restrict__ labels,
                                              const int* __restrict__ counts,
                                              const int* __restrict__ idx,
                                              const float* __restrict__ rnorm,
                                              const float* __restrict__ sums,
                                              const float* __restrict__ snorm2,
                                              float* __restrict__ acc) {
    const int i = blockIdx.x;
    const int c = labels[i];
    const int n = counts[c];
    if (i >= n || n < 2 || i >= RCAP) return;  // no exclusion or contrib==0
    const int k = idx[c * RCAP + i];
    const int t = threadIdx.x;

    const float4 xi = x4[(size_t)i * 256 + t];
    const float4 xk = x4[(size_t)k * 256 + t];
    const float4 s  = ((const float4*)sums)[(size_t)c * 256 + t];

    float d0 = dot4(xi, s);
    float d1 = dot4(xi, xk);
    float d2 = dot4(xk, s);
    float d3 = dot4(xk, xk);
#pragma unroll
    for (int off = 32; off; off >>= 1) {
        d0 += __shfl_xor(d0, off, 64);
        d1 += __shfl_xor(d1, off, 64);
        d2 += __shfl_xor(d2, off, 64);
        d3 += __shfl_xor(d3, off, 64);
    }
    __shared__ float4 wred[4];
    if ((t & 63) == 0) wred[t >> 6] = make_float4(d0, d1, d2, d3);
    __syncthreads();
    if (t == 0) {
        const float xiS  = wred[0].x + wred[1].x + wred[2].x + wred[3].x;
        const float xixk = wred[0].y + wred[1].y + wred[2].y + wred[3].y;
        const float xkS  = wred[0].z + wred[1].z + wred[2].z + wred[3].z;
        const float xkxk = wred[0].w + wred[1].w + wred[2].w + wred[3].w;
        const float rni = rnorm[i], rnk = rnorm[k], s2 = snorm2[c];
        const float fiS  = rni * xiS;
        const float fifk = rni * rnk * xixk;
        const float Sfk  = rnk * xkS;
        const float fk2  = rnk * rnk * xkxk;
        const float nf = (float)n;
        const float dd = nf - 1.0f;
        const float naive = -2.0f * fiS / nf + s2 / (nf * nf);
        const float corr  = -2.0f * (fiS - fifk) / dd + (s2 - 2.0f * Sfk + fk2) / (dd * dd);
        atomicAdd(acc, (corr - naive) * (1.0f / DN));
    }
}

// ---------------------------------------------------------------------------
// K6: finalize scalar output
// ---------------------------------------------------------------------------
__global__ void k_fin(const float* __restrict__ acc, float* __restrict__ out) {
    out[0] = (0.0005f / (float)BN) * acc[0];
}

extern "C" void kernel_launch(void* const* d_in, const int* in_sizes, int n_in,
                              void* d_out, int out_size, void* d_ws, size_t ws_size,
                              hipStream_t stream) {
    const float* features = (const float*)d_in[0];
    const int* labels = (const int*)d_in[1];
    float* out = (float*)d_out;

    // ws layout (bytes):
    char* ws = (char*)d_ws;
    float* rnorm  = (float*)(ws + 0);                 // 32768 f  -> 131072
    float* sums   = (float*)(ws + 131072);            // 262144 f -> +1 MiB = 1179648
    int*   idx    = (int*)  (ws + 1179648);           // 256*1024 i -> +1 MiB = 2228224
    int*   counts = (int*)  (ws + 2228224);           // 256 i -> 2229248
    float* snorm2 = (float*)(ws + 2229248);           // 256 f -> 2230272
    float* acc    = (float*)(ws + 2230272);           // 1 f

    const float4* x4 = (const float4*)features;

    kc_compact<<<CN, 256, 0, stream>>>(labels, idx, counts, acc);
    k_rnorm<<<BN / 4, 256, 0, stream>>>(x4, rnorm);
    k_sums<<<CN, 1024, 0, stream>>>(x4, rnorm, idx, counts, sums, snorm2, acc);
    k_corr<<<2048, 256, 0, stream>>>(x4, labels, counts, idx, rnorm, sums, snorm2, acc);
    k_fin<<<1, 1, 0, stream>>>(acc, out);
}

// Round 3
// 222.111 us; speedup vs baseline: 1.8109x; 1.0401x over previous
//
#include <hip/hip_runtime.h>

// Problem constants (fixed by reference setup_inputs)
#define BN 32768      // batch
#define DN 1024       // feature dim
#define CN 256        // num classes
#define RCAP 512      // max class size tracked (counts ~128 +/- 11; 512 = ~34 sigma)

__device__ __forceinline__ float dot4(float4 a, float4 b) {
    return a.x*b.x + a.y*b.y + a.z*b.z + a.w*b.w;
}

// ---------------------------------------------------------------------------
// K_MAIN: one block (1024 thr / 16 waves) per class. Phases:
//  1) stage all labels to LDS packed as bytes (32 KB), ballot-scan compaction
//     -> ordered member list sic[] (+ global idx/counts for k_corr)
//  2) gather: wave w takes members r = w, w+16, ...: load full 4 KB row,
//     xor-shuffle row norm, write rnorm[row], accumulate x*rn into wave-
//     private regs (features read EXACTLY ONCE from HBM)
//  3) block-reduce wave accumulators via stride-5-padded LDS atomics
//     (conflict-free), write sums[c], snorm2[c]=||S||^2, and add the
//     closed-form class contribution (n - ||S||^2/n)/D to acc.
// ---------------------------------------------------------------------------
__global__ void __launch_bounds__(1024) k_main(const float4* __restrict__ x4,
                                               const int* __restrict__ labels,
                                               int* __restrict__ idx,
                                               int* __restrict__ counts,
                                               float* __restrict__ rnorm,
                                               float* __restrict__ sums,
                                               float* __restrict__ snorm2,
                                               float* __restrict__ acc) {
    __shared__ unsigned int packed[BN / 4];   // 32 KB: 4 labels per word
    __shared__ int sic[RCAP];                 // 2 KB ordered member list
    __shared__ int wcnt[16];
    __shared__ float facc[(DN / 4) * 5];      // 5 KB, stride-5 padded quads
    __shared__ float wred[4];

    const int c = blockIdx.x;
    const int t = threadIdx.x;

    // ---- stage labels (8192 words / 1024 thr = 8 int4 loads each) ----
    for (int w = t; w < BN / 4; w += 1024) {
        const int4 v = ((const int4*)labels)[w];
        packed[w] = (unsigned int)(v.x & 255)
                  | ((unsigned int)(v.y & 255) << 8)
                  | ((unsigned int)(v.z & 255) << 16)
                  | ((unsigned int)(v.w & 255) << 24);
    }
    for (int i = t; i < (DN / 4) * 5; i += 1024) facc[i] = 0.0f;
    __syncthreads();

    const int wave = t >> 6, lane = t & 63;
    const unsigned long long lt = (lane == 0) ? 0ull : (~0ull >> (64 - lane));
    const int ch0 = wave * 32, ch1 = ch0 + 32;  // 32 chunks of 64 per wave

    // ---- pass 1: count ----
    int cnt = 0;
    for (int ch = ch0; ch < ch1; ++ch) {
        const int gi = ch * 64 + lane;
        const int lab = (packed[gi >> 2] >> ((gi & 3) * 8)) & 255;
        cnt += __popcll(__ballot(lab == c));
    }
    if (lane == 0) wcnt[wave] = cnt;
    __syncthreads();

    int base = 0, ntot = 0;
    for (int w2 = 0; w2 < 16; ++w2) {
        const int v = wcnt[w2];
        if (w2 < wave) base += v;
        ntot += v;
    }

    // ---- pass 2: ordered member list (LDS + global for k_corr) ----
    for (int ch = ch0; ch < ch1; ++ch) {
        const int gi = ch * 64 + lane;
        const int lab = (packed[gi >> 2] >> ((gi & 3) * 8)) & 255;
        const bool pred = (lab == c);
        const unsigned long long mask = __ballot(pred);
        if (pred) {
            const int pos = base + __popcll(mask & lt);
            if (pos < RCAP) { sic[pos] = gi; idx[c * RCAP + pos] = gi; }
        }
        base += __popcll(mask);
    }
    if (t == 0) counts[c] = ntot;
    __syncthreads();

    // ---- gather + row norm + scaled accumulate ----
    const int nn = min(ntot, RCAP);
    float4 a0 = make_float4(0.f, 0.f, 0.f, 0.f), a1 = a0, a2 = a0, a3 = a0;
    for (int r = wave; r < nn; r += 16) {
        const int row = sic[r];
        const float4* b4 = x4 + (size_t)row * 256;
        const float4 v0 = b4[lane];
        const float4 v1 = b4[lane + 64];
        const float4 v2 = b4[lane + 128];
        const float4 v3 = b4[lane + 192];
        float ss = dot4(v0, v0) + dot4(v1, v1) + dot4(v2, v2) + dot4(v3, v3);
#pragma unroll
        for (int off = 32; off; off >>= 1) ss += __shfl_xor(ss, off, 64);
        const float rn = 1.0f / fmaxf(sqrtf(ss), 1e-12f);
        if (lane == 0) rnorm[row] = rn;
        a0.x += v0.x * rn; a0.y += v0.y * rn; a0.z += v0.z * rn; a0.w += v0.w * rn;
        a1.x += v1.x * rn; a1.y += v1.y * rn; a1.z += v1.z * rn; a1.w += v1.w * rn;
        a2.x += v2.x * rn; a2.y += v2.y * rn; a2.z += v2.z * rn; a2.w += v2.w * rn;
        a3.x += v3.x * rn; a3.y += v3.y * rn; a3.z += v3.z * rn; a3.w += v3.w * rn;
    }

    // ---- reduce 16 waves into padded LDS (quad q at facc[5q..5q+3]) ----
    {
        const int q0 = lane, q1 = lane + 64, q2 = lane + 128, q3 = lane + 192;
        atomicAdd(&facc[5 * q0 + 0], a0.x); atomicAdd(&facc[5 * q0 + 1], a0.y);
        atomicAdd(&facc[5 * q0 + 2], a0.z); atomicAdd(&facc[5 * q0 + 3], a0.w);
        atomicAdd(&facc[5 * q1 + 0], a1.x); atomicAdd(&facc[5 * q1 + 1], a1.y);
        atomicAdd(&facc[5 * q1 + 2], a1.z); atomicAdd(&facc[5 * q1 + 3], a1.w);
        atomicAdd(&facc[5 * q2 + 0], a2.x); atomicAdd(&facc[5 * q2 + 1], a2.y);
        atomicAdd(&facc[5 * q2 + 2], a2.z); atomicAdd(&facc[5 * q2 + 3], a2.w);
        atomicAdd(&facc[5 * q3 + 0], a3.x); atomicAdd(&facc[5 * q3 + 1], a3.y);
        atomicAdd(&facc[5 * q3 + 2], a3.z); atomicAdd(&facc[5 * q3 + 3], a3.w);
    }
    __syncthreads();

    // ---- write sums, ||S||^2, class contribution ----
    float d = 0.0f;
    if (t < 256) {
        float4 tot;
        tot.x = facc[5 * t + 0]; tot.y = facc[5 * t + 1];
        tot.z = facc[5 * t + 2]; tot.w = facc[5 * t + 3];
        ((float4*)sums)[(size_t)c * 256 + t] = tot;
        d = dot4(tot, tot);
    }
    if (wave < 4) {
#pragma unroll
        for (int off = 32; off; off >>= 1) d += __shfl_xor(d, off, 64);
        if (lane == 0) wred[wave] = d;
    }
    __syncthreads();
    if (t == 0) {
        const float s2 = wred[0] + wred[1] + wred[2] + wred[3];
        snorm2[c] = s2;
        if (ntot > 1) {
            const float nf = (float)ntot;
            atomicAdd(acc, (nf - s2 / nf) * (1.0f / DN));
        }
    }
}

// ---------------------------------------------------------------------------
// K_CORR: exclusion corrections. Row i has exclusion iff i < counts[labels[i]]
// (~128-160 rows, all with global index < ~161). delta = corrected - naive
// dist; ||f_i||^2 cancels. One 256-thread block per candidate row i.
// ---------------------------------------------------------------------------
__global__ void __launch_bounds__(256) k_corr(const float4* __restrict__ x4,
                                              const int* __restrict__ labels,
                                              const int* __restrict__ counts,
                                              const int* __restrict__ idx,
                                              const float* __restrict__ rnorm,
                                              const float* __restrict__ sums,
                                              const float* __restrict__ snorm2,
                                              float* __restrict__ acc) {
    const int i = blockIdx.x;
    const int c = labels[i];
    const int n = counts[c];
    if (i >= n || n < 2 || i >= RCAP) return;  // no exclusion or contrib==0
    const int k = idx[c * RCAP + i];
    const int t = threadIdx.x;

    const float4 xi = x4[(size_t)i * 256 + t];
    const float4 xk = x4[(size_t)k * 256 + t];
    const float4 s  = ((const float4*)sums)[(size_t)c * 256 + t];

    float d0 = dot4(xi, s);
    float d1 = dot4(xi, xk);
    float d2 = dot4(xk, s);
    float d3 = dot4(xk, xk);
#pragma unroll
    for (int off = 32; off; off >>= 1) {
        d0 += __shfl_xor(d0, off, 64);
        d1 += __shfl_xor(d1, off, 64);
        d2 += __shfl_xor(d2, off, 64);
        d3 += __shfl_xor(d3, off, 64);
    }
    __shared__ float4 wred[4];
    if ((t & 63) == 0) wred[t >> 6] = make_float4(d0, d1, d2, d3);
    __syncthreads();
    if (t == 0) {
        const float xiS  = wred[0].x + wred[1].x + wred[2].x + wred[3].x;
        const float xixk = wred[0].y + wred[1].y + wred[2].y + wred[3].y;
        const float xkS  = wred[0].z + wred[1].z + wred[2].z + wred[3].z;
        const float xkxk = wred[0].w + wred[1].w + wred[2].w + wred[3].w;
        const float rni = rnorm[i], rnk = rnorm[k], s2 = snorm2[c];
        const float fiS  = rni * xiS;
        const float fifk = rni * rnk * xixk;
        const float Sfk  = rnk * xkS;
        const float fk2  = rnk * rnk * xkxk;
        const float nf = (float)n;
        const float dd = nf - 1.0f;
        const float naive = -2.0f * fiS / nf + s2 / (nf * nf);
        const float corr  = -2.0f * (fiS - fifk) / dd + (s2 - 2.0f * Sfk + fk2) / (dd * dd);
        atomicAdd(acc, (corr - naive) * (1.0f / DN));
    }
}

// ---------------------------------------------------------------------------
// K_FIN: finalize scalar output
// ---------------------------------------------------------------------------
__global__ void k_fin(const float* __restrict__ acc, float* __restrict__ out) {
    out[0] = (0.0005f / (float)BN) * acc[0];
}

extern "C" void kernel_launch(void* const* d_in, const int* in_sizes, int n_in,
                              void* d_out, int out_size, void* d_ws, size_t ws_size,
                              hipStream_t stream) {
    const float* features = (const float*)d_in[0];
    const int* labels = (const int*)d_in[1];
    float* out = (float*)d_out;

    // ws layout (bytes):
    char* ws = (char*)d_ws;
    float* rnorm  = (float*)(ws + 0);                 // 32768 f  -> 131072
    float* sums   = (float*)(ws + 131072);            // 262144 f -> 1179648
    int*   idx    = (int*)  (ws + 1179648);           // 256*512 i -> 1703936
    int*   counts = (int*)  (ws + 1703936);           // 256 i -> 1704960
    float* snorm2 = (float*)(ws + 1704960);           // 256 f -> 1705984
    float* acc    = (float*)(ws + 1705984);           // 1 f

    const float4* x4 = (const float4*)features;

    hipMemsetAsync(acc, 0, sizeof(float), stream);
    k_main<<<CN, 1024, 0, stream>>>(x4, labels, idx, counts, rnorm, sums, snorm2, acc);
    k_corr<<<RCAP, 256, 0, stream>>>(x4, labels, counts, idx, rnorm, sums, snorm2, acc);
    k_fin<<<1, 1, 0, stream>>>(acc, out);
}